// Round 13
// baseline (262.241 us; speedup 1.0000x reference)
//
#include <hip/hip_runtime.h>

#define NPTS 4096
#define NBATCH 4
#define HDIM 192
#define CDIM 384
#define FINF 3.4e38f

typedef _Float16 f16x8 __attribute__((ext_vector_type(8)));
typedef float f32x4 __attribute__((ext_vector_type(4)));

// ---------------- K0: W2 [192][384] f32 -> fragment-major f16 chunks (R12, unchanged) --
__global__ __launch_bounds__(256) void prep_w2(const float* __restrict__ W2,
                                               _Float16* __restrict__ W2F) {
  const int j = blockIdx.x * 256 + threadIdx.x;   // 9216 chunks
  if (j < 9216) {
    const int lane = j & 63, r = lane & 15, kg = lane >> 4;
    const int kt = (j >> 6) % 6, ct = j / 384;
    const int c = ct * 16 + r, h0 = kt * 32 + kg * 8;
    f16x8 v;
#pragma unroll
    for (int e = 0; e < 8; ++e) v[e] = (_Float16)W2[(size_t)(h0 + e) * CDIM + c];
    *(f16x8*)(W2F + (size_t)j * 8) = v;
  }
}

// ---------------- K0b: per-batch bitonic sort by (x, idx); emit float4{x,y,z,bits(j)} --
__global__ __launch_bounds__(1024) void sort_kernel(const float* __restrict__ pts,
                                                    float4* __restrict__ sp4) {
  __shared__ float kx[4096];
  __shared__ int   ki[4096];
  const int b = blockIdx.x;
  const float* P = pts + (size_t)b * NPTS * 3;
  const int t = threadIdx.x;
  for (int i = t; i < 4096; i += 1024) { kx[i] = P[3 * i]; ki[i] = i; }
  __syncthreads();
  for (int k = 2; k <= 4096; k <<= 1) {
    for (int jj = k >> 1; jj > 0; jj >>= 1) {
      for (int m = t; m < 2048; m += 1024) {
        const int i = ((m & ~(jj - 1)) << 1) | (m & (jj - 1));
        const int p = i | jj;
        const bool up = (i & k) == 0;
        const float xi = kx[i], xp = kx[p];
        const int   ii = ki[i], ip = ki[p];
        const bool gt = (xi > xp) || (xi == xp && ii > ip);   // lex (x, idx): deterministic
        if (gt == up) { kx[i] = xp; kx[p] = xi; ki[i] = ip; ki[p] = ii; }
      }
      __syncthreads();
    }
  }
  for (int i = t; i < 4096; i += 1024) {
    const int j = ki[i];
    sp4[(size_t)b * 4096 + i] =
        make_float4(P[3 * j], P[3 * j + 1], P[3 * j + 2], __uint_as_float((unsigned)j));
  }
}

// ---------------- K1: x-slab KNN ----------------
// 256 blocks x 512 thr. Block = 64 x-sorted queries (group g), 8 waves stride slabs 8-way
// outward from home slab g (64 slabs x 64 cands/batch). Lane owns one query; exact f32
// distance; lexicographic (d, orig j) top-16 (== numpy stable argsort semantics,
// encounter-order independent); stack-decoupled prune; shared per-query threshold;
// slab skip when __all(gap_x^2 > thr*1.0001+1e-6) (sound: d >= dx^2 > thr >= d16).
#define KSCAP 32

#define PRUNE2()                                                                      \
  do {                                                                                \
    int mc = cnt;                                                                     \
    _Pragma("unroll")                                                                 \
    for (int s_ = 32; s_; s_ >>= 1) { int o_ = __shfl_xor(mc, s_); mc = mc > o_ ? mc : o_; } \
    mc = __builtin_amdgcn_readfirstlane(mc);                                          \
    for (int e = 0; e < mc; ++e) {                                                    \
      const bool act = (e < cnt);                                                     \
      const float    dd = act ? dstk[e * 512 + t] : FINF;                             \
      const unsigned jj = act ? (unsigned)jstk[e * 512 + t] : 0xFFFFFFFFu;            \
      bool cc[16];                                                                    \
      _Pragma("unroll")                                                               \
      for (int i = 0; i < 16; ++i)                                                    \
        cc[i] = (dd < dl[i]) || (dd == dl[i] && jj < il[i]);                          \
      _Pragma("unroll")                                                               \
      for (int i = 15; i >= 1; --i) {                                                 \
        dl[i] = cc[i] ? (cc[i - 1] ? dl[i - 1] : dd) : dl[i];                         \
        il[i] = cc[i] ? (cc[i - 1] ? il[i - 1] : jj) : il[i];                         \
      }                                                                               \
      dl[0] = cc[0] ? dd : dl[0];                                                     \
      il[0] = cc[0] ? jj : il[0];                                                     \
    }                                                                                 \
    cnt = 0;                                                                          \
    thr = dl[15];                                                                     \
    atomicMin(&sThrU[l], __float_as_uint(dl[15]));                                    \
  } while (0)

#define PROC_SLAB(S)                                                                  \
  do {                                                                                \
    slab[wv][l] = SP[(S) * 64 + l];   /* coalesced stage; wave-internal */            \
    for (int c0 = 0; c0 < 64; c0 += 16) {                                             \
      const float te = fminf(thr, __uint_as_float(((volatile unsigned*)sThrU)[l]));   \
      _Pragma("unroll")                                                               \
      for (int c = c0; c < c0 + 16; ++c) {                                            \
        const float4 pc = slab[wv][c];                                                \
        const float dx = qx - pc.x;                                                   \
        const float dy = qy - pc.y;                                                   \
        const float dz = qz - pc.z;                                                   \
        /* EXACT reference arithmetic: ((dx*dx+dy*dy)+dz*dz), f32, no FMA */          \
        const float d = __fadd_rn(__fadd_rn(__fmul_rn(dx, dx), __fmul_rn(dy, dy)),    \
                                  __fmul_rn(dz, dz));                                 \
        if (d <= te) {                                                                \
          dstk[cnt * 512 + t] = d;                                                    \
          jstk[cnt * 512 + t] = (unsigned short)__float_as_uint(pc.w);                \
          ++cnt;                                                                      \
        }                                                                             \
      }                                                                               \
      if (__any(cnt >= KSCAP - 16)) PRUNE2();                                         \
    }                                                                                 \
  } while (0)

__global__ __launch_bounds__(512) void knn_kernel(const float4* __restrict__ sp4,
                                                  int* __restrict__ idx_out) {
  __shared__ float          dstk[KSCAP * 512];     // entry-major [e][tid]: 64 KB
  __shared__ unsigned short jstk[KSCAP * 512];     // 32 KB
  __shared__ unsigned       sThrU[64];
  __shared__ float4         slab[8][64];           // per-wave slab buffer, 8 KB

  const int bid = blockIdx.x;              // 256 = 4 batches * 64 groups
  const int b = bid >> 6, g = bid & 63;
  const float4* SP = sp4 + (size_t)b * 4096;
  const int t = threadIdx.x, wv = t >> 6, l = t & 63;

  if (t < 64) sThrU[t] = __float_as_uint(FINF);
  __syncthreads();

  const float4 me = SP[g * 64 + l];
  const float qx = me.x, qy = me.y, qz = me.z;
  const unsigned origq = __float_as_uint(me.w);

  float    dl[16];
  unsigned il[16];
#pragma unroll
  for (int i = 0; i < 16; ++i) { dl[i] = FINF; il[i] = 0xFFFFFFFFu; }
  float thr = FINF;
  int   cnt = 0;

  int  oHi = wv;
  int  oLo = (wv == 0) ? 8 : wv;
  bool hiOpen = (g + oHi) < 64;
  bool loOpen = (g - oLo) >= 0;

  while (hiOpen || loOpen) {
    if (hiOpen) {
      const int s = g + oHi;
      bool skip = false;
      if (oHi > 0) {   // skip test: slab min-x gap (gap >= 0 since slab above all queries)
        const float bx  = SP[s * 64].x;
        const float gap = bx - qx;
        const float te  = fminf(thr, __uint_as_float(((volatile unsigned*)sThrU)[l]));
        skip = __all(__fmul_rn(gap, gap) > te * 1.0001f + 1e-6f);
      }
      if (skip) hiOpen = false;
      else {
        PROC_SLAB(s);
        oHi += 8;
        if (g + oHi >= 64) hiOpen = false;
      }
    }
    if (loOpen) {
      const int s = g - oLo;
      {
        const float bx  = SP[s * 64 + 63].x;   // slab max-x
        const float gap = qx - bx;             // >= 0
        const float te  = fminf(thr, __uint_as_float(((volatile unsigned*)sThrU)[l]));
        if (__all(__fmul_rn(gap, gap) > te * 1.0001f + 1e-6f)) loOpen = false;
      }
      if (loOpen) {
        PROC_SLAB(s);
        oLo += 8;
        if (g - oLo < 0) loOpen = false;
      }
    }
  }
  PRUNE2();   // drain

  __syncthreads();   // stacks dead -> alias merge arrays into them

  // per-wave sorted lists: dm[q*129 + wv*16 + i] (pad 129: bank-spread), jm same layout
  float*          dm = dstk;
  unsigned short* jm = jstk;
  {
    const int base = l * 129 + wv * 16;
#pragma unroll
    for (int i = 0; i < 16; ++i) {
      dm[base + i] = dl[i];
      jm[base + i] = (unsigned short)il[i];   // 0xFFFF for unfilled (d=FINF, loses merges)
    }
  }
  __syncthreads();

  // stage 1: 8 lists -> 4 (256 thr: q=t>>2, h=t&3 merges lists 2h,2h+1)
  float*          om = dstk + 8320;          // [64][4][16] stride 65
  unsigned short* oj = jstk + 8320;
  if (t < 256) {
    const int q = t >> 2, h = t & 3;
    const int bse = q * 129 + h * 32;
    int p0 = 0, p1 = 0;
    const int ob = q * 65 + h * 16;
    for (int r = 0; r < 16; ++r) {
      const float d0 = dm[bse + p0];
      const float d1 = dm[bse + 16 + p1];
      const unsigned short j0 = jm[bse + p0];
      const unsigned short j1 = jm[bse + 16 + p1];
      const bool take1 = (d1 < d0) || (d1 == d0 && j1 < j0);
      om[ob + r] = take1 ? d1 : d0;
      oj[ob + r] = take1 ? j1 : j0;
      p0 += !take1; p1 += take1;
    }
  }
  __syncthreads();

  // stage 2: 4 lists -> 1 (64 thr), write global (row = ORIGINAL query id)
  if (t < 64) {
    const int bse = t * 65;
    int p0 = 0, p1 = 0, p2 = 0, p3 = 0;
    const unsigned oq = __float_as_uint(SP[g * 64 + t].w);
    int* op = idx_out + (((size_t)b * NPTS + oq) << 4);
    for (int r = 0; r < 16; ++r) {
      const float d0 = om[bse + p0];
      const float d1 = om[bse + 16 + p1];
      const float d2 = om[bse + 32 + p2];
      const float d3 = om[bse + 48 + p3];
      const unsigned short j0 = oj[bse + p0];
      const unsigned short j1 = oj[bse + 16 + p1];
      const unsigned short j2 = oj[bse + 32 + p2];
      const unsigned short j3 = oj[bse + 48 + p3];
      float bd = d0; unsigned short bj = j0; int bw = 0;
      if (d1 < bd || (d1 == bd && j1 < bj)) { bd = d1; bj = j1; bw = 1; }
      if (d2 < bd || (d2 == bd && j2 < bj)) { bd = d2; bj = j2; bw = 2; }
      if (d3 < bd || (d3 == bd && j3 < bj)) { bd = d3; bj = j3; bw = 3; }
      op[r] = (int)bj;
      p0 += (bw == 0); p1 += (bw == 1); p2 += (bw == 2); p3 += (bw == 3);
    }
  }
}

// ---------------- K2: fused MLP, ALL of W2 in LDS (R12, unchanged) ----------
__global__ __launch_bounds__(512) void mlp_kernel(const float* __restrict__ pts,
                                                  const int* __restrict__ idx,
                                                  const float* __restrict__ W1,
                                                  const float* __restrict__ b1,
                                                  const _Float16* __restrict__ W2F,
                                                  const float* __restrict__ b2,
                                                  float* __restrict__ out) {
  __shared__ _Float16 sB[73728];       // 144 KiB: all of W2, fragment-major

  const int bid = blockIdx.x;          // 512 = 4 batches * 128 blocks
  const int b   = bid >> 7;
  const int t   = threadIdx.x;
  const int wv  = t >> 6;              // 8 waves
  const int q0  = ((bid & 127) << 5) + (wv << 2);   // 4 queries per wave
  const float* P = pts + (size_t)b * NPTS * 3;
  const int l   = t & 63;
  const int r   = l & 15;
  const int kg  = l >> 4;

#pragma unroll
  for (int i = 0; i < 18; ++i) {
    const int j = i * 512 + t;
    *(f16x8*)(sB + (size_t)j * 8) = *(const f16x8*)(W2F + (size_t)j * 8);
  }

  float f[4][6];
#pragma unroll
  for (int qi = 0; qi < 4; ++qi) {
    const int qq = q0 + qi;
    const int nb = idx[(((size_t)b * NPTS + qq) << 4) + r];
    const float ax = P[qq * 3 + 0], ay = P[qq * 3 + 1], az = P[qq * 3 + 2];
    f[qi][0] = P[nb * 3 + 0] - ax;
    f[qi][1] = P[nb * 3 + 1] - ay;
    f[qi][2] = P[nb * 3 + 2] - az;
    f[qi][3] = ax; f[qi][4] = ay; f[qi][5] = az;
  }

  f16x8 af[4][6];
#pragma unroll
  for (int kt = 0; kt < 6; ++kt) {
    const int h0 = kt * 32 + kg * 8;
    const f32x4 bb0 = *(const f32x4*)(b1 + h0);
    const f32x4 bb1 = *(const f32x4*)(b1 + h0 + 4);
    f32x4 w0[6], w1[6];
#pragma unroll
    for (int in = 0; in < 6; ++in) {
      w0[in] = *(const f32x4*)(W1 + in * HDIM + h0);
      w1[in] = *(const f32x4*)(W1 + in * HDIM + h0 + 4);
    }
#pragma unroll
    for (int qi = 0; qi < 4; ++qi) {
      f32x4 a0 = bb0, a1 = bb1;
#pragma unroll
      for (int in = 0; in < 6; ++in) {
        a0 += f[qi][in] * w0[in];
        a1 += f[qi][in] * w1[in];
      }
      f16x8 v;
#pragma unroll
      for (int j = 0; j < 4; ++j) {
        v[j]     = (_Float16)(a0[j] * __builtin_amdgcn_rcpf(1.0f + __expf(-a0[j])));
        v[j + 4] = (_Float16)(a1[j] * __builtin_amdgcn_rcpf(1.0f + __expf(-a1[j])));
      }
      af[qi][kt] = v;
    }
  }
  __syncthreads();

  const size_t orow = (size_t)b * NPTS + q0;
  const _Float16* bp = sB + (size_t)l * 8;

  for (int ct = 0; ct < 24; ++ct) {
    const int c = ct * 16 + r;
    f16x8 bfr[6];
#pragma unroll
    for (int kt = 0; kt < 6; ++kt)
      bfr[kt] = *(const f16x8*)(bp + (size_t)(ct * 6 + kt) * 512);

    f32x4 acc[4];
#pragma unroll
    for (int qi = 0; qi < 4; ++qi) acc[qi] = f32x4{0.f, 0.f, 0.f, 0.f};
#pragma unroll
    for (int kt = 0; kt < 6; ++kt)
#pragma unroll
      for (int qi = 0; qi < 4; ++qi)
        acc[qi] = __builtin_amdgcn_mfma_f32_16x16x32_f16(af[qi][kt], bfr[kt], acc[qi], 0, 0, 0);

    const float bb = b2[c];
#pragma unroll
    for (int qi = 0; qi < 4; ++qi) {
      float m = fmaxf(fmaxf(acc[qi][0], acc[qi][1]), fmaxf(acc[qi][2], acc[qi][3]));
      m = fmaxf(m, __shfl_xor(m, 16));
      m = fmaxf(m, __shfl_xor(m, 32));
      if (l < 16)
        out[(orow + qi) * CDIM + c] = m + bb;
    }
  }
}

extern "C" void kernel_launch(void* const* d_in, const int* in_sizes, int n_in,
                              void* d_out, int out_size, void* d_ws, size_t ws_size,
                              hipStream_t stream) {
  const float* point = (const float*)d_in[0];
  const float* W1    = (const float*)d_in[1];
  const float* b1    = (const float*)d_in[2];
  const float* W2    = (const float*)d_in[3];
  const float* b2    = (const float*)d_in[4];

  int*      idx_ws = (int*)d_ws;                                  // 1 MB
  float4*   sp4    = (float4*)((char*)d_ws + (1 << 20));          // 256 KB
  _Float16* W2F    = (_Float16*)((char*)d_ws + (1 << 20) + (256 << 10));  // 144 KB

  prep_w2<<<36, 256, 0, stream>>>(W2, W2F);
  sort_kernel<<<NBATCH, 1024, 0, stream>>>(point, sp4);
  knn_kernel<<<256, 512, 0, stream>>>(sp4, idx_ws);
  mlp_kernel<<<512, 512, 0, stream>>>(point, idx_ws, W1, b1, W2F, b2, (float*)d_out);
}